// Round 18
// baseline (103.512 us; speedup 1.0000x reference)
//
#include <hip/hip_runtime.h>
#include <hip/hip_fp16.h>

// total = l1 + 0.5*(1 - mean(ssim3d)), volumes (4,1,128,128,128) f32
// SSIM window 11, zero-padded box sums, /11^3.
//
// 4-field formulation: stage A=sum(p+t), D=sum(p-t), U=sum((p+t)^2),
// V=sum((p-t)^2).  Then 2*mu_p*mu_t=(muA^2-muD^2)/2, mu_p^2+mu_t^2=
// (muA^2+muD^2)/2, sig_p+sig_t=(U+V)*INV/2-S2, 2*sig_pt=(U-V)*INV/2-P2.
// f16 intermediates: ranges <= 5324, rel err 4.9e-4, unbiased; final scalar
// err ~1e-4 << 1.8e-2 threshold.
//
// This is the R12 champion (57.55us measured) with ONE change:
// __launch_bounds__(256, 8) on k_wh. R12 capped residency at 4 blocks/CU
// (50% occ, measured 36.7%); LDS 18.4KB and VGPR 44 both fit 8 blocks/CU.
// R6: no last-block merge (device fence flushes per-XCD L2).

#define NB 4
#define ND 128
#define NH 128
#define NW 128
#define PLANE (NH * NW)            // 16384
#define VOL (ND * PLANE)           // 2,097,152
#define VOL4 (NB * VOL)            // 8,388,608
#define K1_BLOCKS (NB * ND * 8)    // 4096 (h tiled by 16)
#define K2_BLOCKS 1024             // 8 d-chunks of 16 x 128 (b,h) groups
#define HS_F16 142                 // f16 row stride = 71 words (odd, 7 mod 32)

typedef _Float16 half2v __attribute__((ext_vector_type(2)));
typedef float f32x2 __attribute__((ext_vector_type(2)));

// ---------------- Kernel 1: fused W+H box sums of 4 fields + L1 partials ----
// Stage A: 4 waves x 4 output rows, 2 w-cols/lane. All 28 window loads issued
//          up front, halo-zero DS writes overlap the load flight, then
//          A/D/U/V sums, packed b32 f16-pair LDS writes.
// Stage B: 10 b32 reads/field; word = 71*ho + 4*wc + m; 71*ho mod 4 distinct
//          across a wave's 4 ho values -> disjoint bank groups, 2-way, free.
__global__ __launch_bounds__(256, 8) void k_wh(const float* __restrict__ p,
                                               const float* __restrict__ t,
                                               _Float16* __restrict__ S5,
                                               float* __restrict__ l1p)
{
    __shared__ _Float16 hs[4][16][HS_F16];   // 18,176 B
    __shared__ float red4[4];

    const int bid   = blockIdx.x;
    const int htile = bid & 7;
    const int d     = (bid >> 3) & 127;
    const int b     = bid >> 10;
    const int h0    = htile * 16;
    const int tid   = threadIdx.x;

    // ---- Stage A ----
    const int wp = tid & 63;          // lane: owns w = 2*wp, 2*wp+1
    const int c  = tid >> 6;          // wave: owns output rows hbase..hbase+3
    const int hbase = h0 + c * 4;
    const int pbase = ((b * ND + d) * NH) * NW + 2 * wp;
    const int wcol  = 2 * wp + 6;

    const f32x2 z2 = {0.f, 0.f};

    // Issue ALL 28 window loads first (guards are wave-uniform).
    f32x2 P[14], T[14];
#pragma unroll
    for (int i = 0; i < 14; ++i) {
        const int h = hbase - 5 + i;
        f32x2 pv = z2, tv = z2;
        if (h >= 0 && h < NH) {
            pv = *(const f32x2*)&p[pbase + h * NW];
            tv = *(const f32x2*)&t[pbase + h * NW];
        }
        P[i] = pv; T[i] = tv;
    }
    __builtin_amdgcn_sched_barrier(0);   // loads may not sink below this

    // halo zero (DS writes execute while loads are in flight):
    // cols 0..5 (w<0) and 134..141 (w>=128)
    for (int idx = tid; idx < 4 * 16 * 14; idx += 256) {
        const int f = idx / 224;
        const int rem = idx - f * 224;
        const int r = rem / 14;
        const int c14 = rem - r * 14;
        const int col = (c14 < 6) ? c14 : (128 + c14);
        hs[f][r][col] = (_Float16)0.f;
    }
    __builtin_amdgcn_sched_barrier(0);   // compute may not hoist above

    // Transform to A/D once; P/T die here.
    f32x2 A_[14], D_[14];
#pragma unroll
    for (int i = 0; i < 14; ++i) {
        A_[i] = P[i] + T[i];
        D_[i] = P[i] - T[i];
    }

    // L1 center taps: owned rows hbase..hbase+3 = window idx 5..8
    float l1x = 0.f, l1y = 0.f;
#pragma unroll
    for (int i = 5; i <= 8; ++i) {
        l1x += fabsf(D_[i].x);
        l1y += fabsf(D_[i].y);
    }

    f32x2 sA = z2, sD = z2, sU = z2, sV = z2;
#pragma unroll
    for (int i = 0; i < 11; ++i) {
        const f32x2 a = A_[i], dd = D_[i];
        sA += a; sD += dd;
        sU += a * a; sV += dd * dd;
    }

#define STORE4(r) do {                                                        \
        half2v o_;                                                            \
        o_[0] = (_Float16)sA.x; o_[1] = (_Float16)sA.y;                       \
        *(half2v*)&hs[0][(r)][wcol] = o_;                                     \
        o_[0] = (_Float16)sD.x; o_[1] = (_Float16)sD.y;                       \
        *(half2v*)&hs[1][(r)][wcol] = o_;                                     \
        o_[0] = (_Float16)sU.x; o_[1] = (_Float16)sU.y;                       \
        *(half2v*)&hs[2][(r)][wcol] = o_;                                     \
        o_[0] = (_Float16)sV.x; o_[1] = (_Float16)sV.y;                       \
        *(half2v*)&hs[3][(r)][wcol] = o_;                                     \
    } while (0)

    STORE4(c * 4);
#pragma unroll
    for (int k = 1; k < 4; ++k) {
        const f32x2 an = A_[10 + k], dn = D_[10 + k];
        const f32x2 ao = A_[k - 1],  do_ = D_[k - 1];
        sA += an - ao;
        sD += dn - do_;
        sU += an * an - ao * ao;
        sV += dn * dn - do_ * do_;
        STORE4(c * 4 + k);
    }
#undef STORE4

    // ---- L1 reduce: in-wave shuffle, one barrier ----
    {
        float v = l1x + l1y;
#pragma unroll
        for (int off = 32; off > 0; off >>= 1) v += __shfl_down(v, off, 64);
        if ((tid & 63) == 0) red4[tid >> 6] = v;
    }
    __syncthreads();          // publishes hs (stage A + halo) and red4
    if (tid == 0) l1p[bid] = red4[0] + red4[1] + red4[2] + red4[3];

    // ---- Stage B: W-direction sliding sums from LDS pairs, f16 stores ----
    const int ho = tid >> 4;          // 0..15
    const int wc = tid & 15;          // owns w in [8*wc, 8*wc+8)
    const size_t obase = (size_t)((b * ND + d) * NH + (h0 + ho)) * NW + wc * 8;

#pragma unroll
    for (int f = 0; f < 4; ++f) {
        half2v pr[10];
#pragma unroll
        for (int m = 0; m < 10; ++m)
            pr[m] = *(const half2v*)&hs[f][ho][8 * wc + 2 * m];
        // v[k] = H-sum at w = 8*wc - 5 + k  (halo cols are pre-zeroed)
        float v[18];
#pragma unroll
        for (int k = 0; k < 18; ++k)
            v[k] = (k & 1) ? (float)pr[(k + 1) >> 1][0] : (float)pr[k >> 1][1];
        float s = 0.f;
#pragma unroll
        for (int j = 0; j < 11; ++j) s += v[j];
        union { _Float16 h8[8]; uint4 u; } o;
        o.h8[0] = (_Float16)s;
#pragma unroll
        for (int n = 1; n < 8; ++n) {
            s += v[10 + n] - v[n - 1];
            o.h8[n] = (_Float16)s;
        }
        *(uint4*)&S5[(size_t)f * VOL4 + obase] = o.u;
    }
    // no trailing barrier: stores drain at endpgm
}

// ---------------- Kernel 2: D-direction sliding window + SSIM + reduce ------
// Register ring of the 11-plane window (statically indexed, full unroll).
__global__ __launch_bounds__(256) void k_d_ssim(const _Float16* __restrict__ S5,
                                                float* __restrict__ ssimp)
{
    __shared__ float red4[4];
    const float INV  = 1.0f / 1331.0f;
    const float INV2 = 1.0f / 2662.0f;
    const float C1f = 1e-4f, C2f = 9e-4f;

    const int bid = blockIdx.x;      // 1024 blocks
    const int dc  = bid & 7;         // d chunk (16 deep)
    const int tid = threadIdx.x;
    const int idx = ((bid >> 3) << 8) + tid;   // 0..32767 -> (b,h,wpair)
    const int wp = idx & 63;
    const int h  = (idx >> 6) & 127;
    const int b  = idx >> 13;
    const int d0 = dc * 16;
    const size_t base0 = (size_t)b * VOL + h * NW + wp * 2;

    const _Float16* F0 = S5 + 0 * (size_t)VOL4 + base0;   // A
    const _Float16* F1 = S5 + 1 * (size_t)VOL4 + base0;   // D
    const _Float16* F2 = S5 + 2 * (size_t)VOL4 + base0;   // U
    const _Float16* F3 = S5 + 3 * (size_t)VOL4 + base0;   // V

#define LOADF(F, dd) (*(const half2v*)&(F)[(size_t)(dd) * PLANE])

    half2v ring[4][11];               // window planes, slot = (plane-(d0-5))%11
    float rsx[4] = {0.f, 0.f, 0.f, 0.f};
    float rsy[4] = {0.f, 0.f, 0.f, 0.f};

#pragma unroll
    for (int o = -5; o <= 5; ++o) {
        const int dd = d0 + o;
        half2v v0, v1, v2, v3;
        if (dd >= 0 && dd < ND) {
            v0 = LOADF(F0, dd); v1 = LOADF(F1, dd);
            v2 = LOADF(F2, dd); v3 = LOADF(F3, dd);
        } else {
            v0 = v1 = v2 = v3 = (half2v)(_Float16)0.f;
        }
        ring[0][o + 5] = v0; ring[1][o + 5] = v1;
        ring[2][o + 5] = v2; ring[3][o + 5] = v3;
        rsx[0] += (float)v0[0]; rsy[0] += (float)v0[1];
        rsx[1] += (float)v1[0]; rsy[1] += (float)v1[1];
        rsx[2] += (float)v2[0]; rsy[2] += (float)v2[1];
        rsx[3] += (float)v3[0]; rsy[3] += (float)v3[1];
    }

    float acc = 0.f;
#pragma unroll
    for (int s = 0; s < 16; ++s) {
        {
            const float muA = rsx[0] * INV, muD = rsx[1] * INV;
            const float mAA = muA * muA, mDD = muD * muD;
            const float P2 = 0.5f * (mAA - mDD);     // 2 mu_p mu_t
            const float S2 = 0.5f * (mAA + mDD);     // mu_p^2 + mu_t^2
            const float num = (P2 + C1f) * fmaf(rsx[2] - rsx[3], INV2, C2f - P2);
            const float den = (S2 + C1f) * fmaf(rsx[2] + rsx[3], INV2, C2f - S2);
            acc = fmaf(num, __builtin_amdgcn_rcpf(den), acc);
        }
        {
            const float muA = rsy[0] * INV, muD = rsy[1] * INV;
            const float mAA = muA * muA, mDD = muD * muD;
            const float P2 = 0.5f * (mAA - mDD);
            const float S2 = 0.5f * (mAA + mDD);
            const float num = (P2 + C1f) * fmaf(rsy[2] - rsy[3], INV2, C2f - P2);
            const float den = (S2 + C1f) * fmaf(rsy[2] + rsy[3], INV2, C2f - S2);
            acc = fmaf(num, __builtin_amdgcn_rcpf(den), acc);
        }

        if (s < 15) {
            const int slot = s % 11;
            const int da = d0 + 6 + s;
            half2v n0, n1, n2, n3;
            if (da < ND) {
                n0 = LOADF(F0, da); n1 = LOADF(F1, da);
                n2 = LOADF(F2, da); n3 = LOADF(F3, da);
            } else {
                n0 = n1 = n2 = n3 = (half2v)(_Float16)0.f;
            }
            rsx[0] += (float)n0[0] - (float)ring[0][slot][0];
            rsy[0] += (float)n0[1] - (float)ring[0][slot][1];
            rsx[1] += (float)n1[0] - (float)ring[1][slot][0];
            rsy[1] += (float)n1[1] - (float)ring[1][slot][1];
            rsx[2] += (float)n2[0] - (float)ring[2][slot][0];
            rsy[2] += (float)n2[1] - (float)ring[2][slot][1];
            rsx[3] += (float)n3[0] - (float)ring[3][slot][0];
            rsy[3] += (float)n3[1] - (float)ring[3][slot][1];
            ring[0][slot] = n0; ring[1][slot] = n1;
            ring[2][slot] = n2; ring[3][slot] = n3;
        }
    }
#undef LOADF

    // in-wave shuffle reduce, one barrier
    float v = acc;
#pragma unroll
    for (int off = 32; off > 0; off >>= 1) v += __shfl_down(v, off, 64);
    if ((tid & 63) == 0) red4[tid >> 6] = v;
    __syncthreads();
    if (tid == 0) ssimp[bid] = red4[0] + red4[1] + red4[2] + red4[3];
}

// ---------------- Kernel 3: final deterministic reduction -------------------
__global__ __launch_bounds__(256) void k_final(const float* __restrict__ l1p,
                                               const float* __restrict__ sp,
                                               float* __restrict__ out)
{
    __shared__ double r1[256];
    __shared__ double r2[256];
    const int tid = threadIdx.x;
    double s1 = 0.0, s2 = 0.0;
    for (int i = tid; i < K1_BLOCKS; i += 256) s1 += (double)l1p[i];
    for (int i = tid; i < K2_BLOCKS; i += 256) s2 += (double)sp[i];
    r1[tid] = s1; r2[tid] = s2;
    __syncthreads();
    for (int s = 128; s > 0; s >>= 1) {
        if (tid < s) { r1[tid] += r1[tid + s]; r2[tid] += r2[tid + s]; }
        __syncthreads();
    }
    if (tid == 0) {
        const double N = (double)VOL4;
        const double l1        = r1[0] / N;
        const double ssim_mean = r2[0] / N;
        const double ssim_loss = 1.0 - ssim_mean;
        out[0] = (float)(l1 + 0.5 * ssim_loss);  // total
        out[1] = (float)l1;                      // l1_loss
        out[2] = (float)ssim_loss;               // ssim_loss
        out[3] = 0.f;                            // reg_loss
    }
}

extern "C" void kernel_launch(void* const* d_in, const int* in_sizes, int n_in,
                              void* d_out, int out_size, void* d_ws, size_t ws_size,
                              hipStream_t stream)
{
    const float* pred = (const float*)d_in[0];
    const float* targ = (const float*)d_in[1];
    float* out = (float*)d_out;

    _Float16* S5 = (_Float16*)d_ws;                       // 4*VOL4*2B = 67.1 MB
    float* l1p   = (float*)((char*)d_ws + (size_t)4 * VOL4 * 2);
    float* ssimp = l1p + K1_BLOCKS;

    k_wh<<<K1_BLOCKS, 256, 0, stream>>>(pred, targ, S5, l1p);
    k_d_ssim<<<K2_BLOCKS, 256, 0, stream>>>(S5, ssimp);
    k_final<<<1, 256, 0, stream>>>(l1p, ssimp, out);
}

// Round 19
// 56.732 us; speedup vs baseline: 1.8246x; 1.8246x over previous
//
#include <hip/hip_runtime.h>
#include <hip/hip_fp16.h>

// total = l1 + 0.5*(1 - mean(ssim3d)), volumes (4,1,128,128,128) f32
// SSIM window 11, zero-padded box sums, /11^3.
//
// 4-field formulation: stage A=sum(p+t), D=sum(p-t), U=sum((p+t)^2),
// V=sum((p-t)^2).  Then 2*mu_p*mu_t=(muA^2-muD^2)/2, mu_p^2+mu_t^2=
// (muA^2+muD^2)/2, sig_p+sig_t=(U+V)*INV/2-S2, 2*sig_pt=(U-V)*INV/2-P2.
// f16 intermediates: ranges <= 5324, rel err 4.9e-4, unbiased; final scalar
// err ~1e-4 << 1.8e-2 threshold.
//
// === R12 CHAMPION RESTORED (57.55us measured) ===
// R6:  no last-block merge (device fence flushes per-XCD L2: k2 17->68us).
// R18: __launch_bounds__(256,8) forced VGPR 44->32, spilled the preload
//      arrays (WRITE 66->222MB, 43->104us). (256,4) is the right bound.
// R8-R17: barriers / DS-count / reg-preload / wide-tile / LDS-DMA / float4 /
//      paired-store variants all regressed or neutral; this config is the
//      measured optimum of the explored space.

#define NB 4
#define ND 128
#define NH 128
#define NW 128
#define PLANE (NH * NW)            // 16384
#define VOL (ND * PLANE)           // 2,097,152
#define VOL4 (NB * VOL)            // 8,388,608
#define K1_BLOCKS (NB * ND * 8)    // 4096 (h tiled by 16)
#define K2_BLOCKS 1024             // 8 d-chunks of 16 x 128 (b,h) groups
#define HS_F16 142                 // f16 row stride = 71 words (odd, 7 mod 32)

typedef _Float16 half2v __attribute__((ext_vector_type(2)));
typedef float f32x2 __attribute__((ext_vector_type(2)));

// ---------------- Kernel 1: fused W+H box sums of 4 fields + L1 partials ----
// Stage A: 4 waves x 4 output rows, 2 w-cols/lane. All 28 window loads issued
//          up front (sched_barrier-pinned), halo-zero DS writes overlap the
//          load flight, then A/D/U/V sums, packed b32 f16-pair LDS writes.
// Stage B: 10 b32 reads/field; word = 71*ho + 4*wc + m; 71*ho mod 4 distinct
//          across a wave's 4 ho values -> disjoint bank groups, 2-way, free.
__global__ __launch_bounds__(256, 4) void k_wh(const float* __restrict__ p,
                                               const float* __restrict__ t,
                                               _Float16* __restrict__ S5,
                                               float* __restrict__ l1p)
{
    __shared__ _Float16 hs[4][16][HS_F16];   // 18,176 B
    __shared__ float red4[4];

    const int bid   = blockIdx.x;
    const int htile = bid & 7;
    const int d     = (bid >> 3) & 127;
    const int b     = bid >> 10;
    const int h0    = htile * 16;
    const int tid   = threadIdx.x;

    // ---- Stage A ----
    const int wp = tid & 63;          // lane: owns w = 2*wp, 2*wp+1
    const int c  = tid >> 6;          // wave: owns output rows hbase..hbase+3
    const int hbase = h0 + c * 4;
    const int pbase = ((b * ND + d) * NH) * NW + 2 * wp;
    const int wcol  = 2 * wp + 6;

    const f32x2 z2 = {0.f, 0.f};

    // Issue ALL 28 window loads first (guards are wave-uniform).
    f32x2 P[14], T[14];
#pragma unroll
    for (int i = 0; i < 14; ++i) {
        const int h = hbase - 5 + i;
        f32x2 pv = z2, tv = z2;
        if (h >= 0 && h < NH) {
            pv = *(const f32x2*)&p[pbase + h * NW];
            tv = *(const f32x2*)&t[pbase + h * NW];
        }
        P[i] = pv; T[i] = tv;
    }
    __builtin_amdgcn_sched_barrier(0);   // loads may not sink below this

    // halo zero (DS writes execute while loads are in flight):
    // cols 0..5 (w<0) and 134..141 (w>=128)
    for (int idx = tid; idx < 4 * 16 * 14; idx += 256) {
        const int f = idx / 224;
        const int rem = idx - f * 224;
        const int r = rem / 14;
        const int c14 = rem - r * 14;
        const int col = (c14 < 6) ? c14 : (128 + c14);
        hs[f][r][col] = (_Float16)0.f;
    }
    __builtin_amdgcn_sched_barrier(0);   // compute may not hoist above

    // Transform to A/D once; P/T die here.
    f32x2 A_[14], D_[14];
#pragma unroll
    for (int i = 0; i < 14; ++i) {
        A_[i] = P[i] + T[i];
        D_[i] = P[i] - T[i];
    }

    // L1 center taps: owned rows hbase..hbase+3 = window idx 5..8
    float l1x = 0.f, l1y = 0.f;
#pragma unroll
    for (int i = 5; i <= 8; ++i) {
        l1x += fabsf(D_[i].x);
        l1y += fabsf(D_[i].y);
    }

    f32x2 sA = z2, sD = z2, sU = z2, sV = z2;
#pragma unroll
    for (int i = 0; i < 11; ++i) {
        const f32x2 a = A_[i], dd = D_[i];
        sA += a; sD += dd;
        sU += a * a; sV += dd * dd;
    }

#define STORE4(r) do {                                                        \
        half2v o_;                                                            \
        o_[0] = (_Float16)sA.x; o_[1] = (_Float16)sA.y;                       \
        *(half2v*)&hs[0][(r)][wcol] = o_;                                     \
        o_[0] = (_Float16)sD.x; o_[1] = (_Float16)sD.y;                       \
        *(half2v*)&hs[1][(r)][wcol] = o_;                                     \
        o_[0] = (_Float16)sU.x; o_[1] = (_Float16)sU.y;                       \
        *(half2v*)&hs[2][(r)][wcol] = o_;                                     \
        o_[0] = (_Float16)sV.x; o_[1] = (_Float16)sV.y;                       \
        *(half2v*)&hs[3][(r)][wcol] = o_;                                     \
    } while (0)

    STORE4(c * 4);
#pragma unroll
    for (int k = 1; k < 4; ++k) {
        const f32x2 an = A_[10 + k], dn = D_[10 + k];
        const f32x2 ao = A_[k - 1],  do_ = D_[k - 1];
        sA += an - ao;
        sD += dn - do_;
        sU += an * an - ao * ao;
        sV += dn * dn - do_ * do_;
        STORE4(c * 4 + k);
    }
#undef STORE4

    // ---- L1 reduce: in-wave shuffle, one barrier ----
    {
        float v = l1x + l1y;
#pragma unroll
        for (int off = 32; off > 0; off >>= 1) v += __shfl_down(v, off, 64);
        if ((tid & 63) == 0) red4[tid >> 6] = v;
    }
    __syncthreads();          // publishes hs (stage A + halo) and red4
    if (tid == 0) l1p[bid] = red4[0] + red4[1] + red4[2] + red4[3];

    // ---- Stage B: W-direction sliding sums from LDS pairs, f16 stores ----
    const int ho = tid >> 4;          // 0..15
    const int wc = tid & 15;          // owns w in [8*wc, 8*wc+8)
    const size_t obase = (size_t)((b * ND + d) * NH + (h0 + ho)) * NW + wc * 8;

#pragma unroll
    for (int f = 0; f < 4; ++f) {
        half2v pr[10];
#pragma unroll
        for (int m = 0; m < 10; ++m)
            pr[m] = *(const half2v*)&hs[f][ho][8 * wc + 2 * m];
        // v[k] = H-sum at w = 8*wc - 5 + k  (halo cols are pre-zeroed)
        float v[18];
#pragma unroll
        for (int k = 0; k < 18; ++k)
            v[k] = (k & 1) ? (float)pr[(k + 1) >> 1][0] : (float)pr[k >> 1][1];
        float s = 0.f;
#pragma unroll
        for (int j = 0; j < 11; ++j) s += v[j];
        union { _Float16 h8[8]; uint4 u; } o;
        o.h8[0] = (_Float16)s;
#pragma unroll
        for (int n = 1; n < 8; ++n) {
            s += v[10 + n] - v[n - 1];
            o.h8[n] = (_Float16)s;
        }
        *(uint4*)&S5[(size_t)f * VOL4 + obase] = o.u;
    }
    // no trailing barrier: stores drain at endpgm
}

// ---------------- Kernel 2: D-direction sliding window + SSIM + reduce ------
// Register ring of the 11-plane window (statically indexed, full unroll).
__global__ __launch_bounds__(256) void k_d_ssim(const _Float16* __restrict__ S5,
                                                float* __restrict__ ssimp)
{
    __shared__ float red4[4];
    const float INV  = 1.0f / 1331.0f;
    const float INV2 = 1.0f / 2662.0f;
    const float C1f = 1e-4f, C2f = 9e-4f;

    const int bid = blockIdx.x;      // 1024 blocks
    const int dc  = bid & 7;         // d chunk (16 deep)
    const int tid = threadIdx.x;
    const int idx = ((bid >> 3) << 8) + tid;   // 0..32767 -> (b,h,wpair)
    const int wp = idx & 63;
    const int h  = (idx >> 6) & 127;
    const int b  = idx >> 13;
    const int d0 = dc * 16;
    const size_t base0 = (size_t)b * VOL + h * NW + wp * 2;

    const _Float16* F0 = S5 + 0 * (size_t)VOL4 + base0;   // A
    const _Float16* F1 = S5 + 1 * (size_t)VOL4 + base0;   // D
    const _Float16* F2 = S5 + 2 * (size_t)VOL4 + base0;   // U
    const _Float16* F3 = S5 + 3 * (size_t)VOL4 + base0;   // V

#define LOADF(F, dd) (*(const half2v*)&(F)[(size_t)(dd) * PLANE])

    half2v ring[4][11];               // window planes, slot = (plane-(d0-5))%11
    float rsx[4] = {0.f, 0.f, 0.f, 0.f};
    float rsy[4] = {0.f, 0.f, 0.f, 0.f};

#pragma unroll
    for (int o = -5; o <= 5; ++o) {
        const int dd = d0 + o;
        half2v v0, v1, v2, v3;
        if (dd >= 0 && dd < ND) {
            v0 = LOADF(F0, dd); v1 = LOADF(F1, dd);
            v2 = LOADF(F2, dd); v3 = LOADF(F3, dd);
        } else {
            v0 = v1 = v2 = v3 = (half2v)(_Float16)0.f;
        }
        ring[0][o + 5] = v0; ring[1][o + 5] = v1;
        ring[2][o + 5] = v2; ring[3][o + 5] = v3;
        rsx[0] += (float)v0[0]; rsy[0] += (float)v0[1];
        rsx[1] += (float)v1[0]; rsy[1] += (float)v1[1];
        rsx[2] += (float)v2[0]; rsy[2] += (float)v2[1];
        rsx[3] += (float)v3[0]; rsy[3] += (float)v3[1];
    }

    float acc = 0.f;
#pragma unroll
    for (int s = 0; s < 16; ++s) {
        {
            const float muA = rsx[0] * INV, muD = rsx[1] * INV;
            const float mAA = muA * muA, mDD = muD * muD;
            const float P2 = 0.5f * (mAA - mDD);     // 2 mu_p mu_t
            const float S2 = 0.5f * (mAA + mDD);     // mu_p^2 + mu_t^2
            const float num = (P2 + C1f) * fmaf(rsx[2] - rsx[3], INV2, C2f - P2);
            const float den = (S2 + C1f) * fmaf(rsx[2] + rsx[3], INV2, C2f - S2);
            acc = fmaf(num, __builtin_amdgcn_rcpf(den), acc);
        }
        {
            const float muA = rsy[0] * INV, muD = rsy[1] * INV;
            const float mAA = muA * muA, mDD = muD * muD;
            const float P2 = 0.5f * (mAA - mDD);
            const float S2 = 0.5f * (mAA + mDD);
            const float num = (P2 + C1f) * fmaf(rsy[2] - rsy[3], INV2, C2f - P2);
            const float den = (S2 + C1f) * fmaf(rsy[2] + rsy[3], INV2, C2f - S2);
            acc = fmaf(num, __builtin_amdgcn_rcpf(den), acc);
        }

        if (s < 15) {
            const int slot = s % 11;
            const int da = d0 + 6 + s;
            half2v n0, n1, n2, n3;
            if (da < ND) {
                n0 = LOADF(F0, da); n1 = LOADF(F1, da);
                n2 = LOADF(F2, da); n3 = LOADF(F3, da);
            } else {
                n0 = n1 = n2 = n3 = (half2v)(_Float16)0.f;
            }
            rsx[0] += (float)n0[0] - (float)ring[0][slot][0];
            rsy[0] += (float)n0[1] - (float)ring[0][slot][1];
            rsx[1] += (float)n1[0] - (float)ring[1][slot][0];
            rsy[1] += (float)n1[1] - (float)ring[1][slot][1];
            rsx[2] += (float)n2[0] - (float)ring[2][slot][0];
            rsy[2] += (float)n2[1] - (float)ring[2][slot][1];
            rsx[3] += (float)n3[0] - (float)ring[3][slot][0];
            rsy[3] += (float)n3[1] - (float)ring[3][slot][1];
            ring[0][slot] = n0; ring[1][slot] = n1;
            ring[2][slot] = n2; ring[3][slot] = n3;
        }
    }
#undef LOADF

    // in-wave shuffle reduce, one barrier
    float v = acc;
#pragma unroll
    for (int off = 32; off > 0; off >>= 1) v += __shfl_down(v, off, 64);
    if ((tid & 63) == 0) red4[tid >> 6] = v;
    __syncthreads();
    if (tid == 0) ssimp[bid] = red4[0] + red4[1] + red4[2] + red4[3];
}

// ---------------- Kernel 3: final deterministic reduction -------------------
__global__ __launch_bounds__(256) void k_final(const float* __restrict__ l1p,
                                               const float* __restrict__ sp,
                                               float* __restrict__ out)
{
    __shared__ double r1[256];
    __shared__ double r2[256];
    const int tid = threadIdx.x;
    double s1 = 0.0, s2 = 0.0;
    for (int i = tid; i < K1_BLOCKS; i += 256) s1 += (double)l1p[i];
    for (int i = tid; i < K2_BLOCKS; i += 256) s2 += (double)sp[i];
    r1[tid] = s1; r2[tid] = s2;
    __syncthreads();
    for (int s = 128; s > 0; s >>= 1) {
        if (tid < s) { r1[tid] += r1[tid + s]; r2[tid] += r2[tid + s]; }
        __syncthreads();
    }
    if (tid == 0) {
        const double N = (double)VOL4;
        const double l1        = r1[0] / N;
        const double ssim_mean = r2[0] / N;
        const double ssim_loss = 1.0 - ssim_mean;
        out[0] = (float)(l1 + 0.5 * ssim_loss);  // total
        out[1] = (float)l1;                      // l1_loss
        out[2] = (float)ssim_loss;               // ssim_loss
        out[3] = 0.f;                            // reg_loss
    }
}

extern "C" void kernel_launch(void* const* d_in, const int* in_sizes, int n_in,
                              void* d_out, int out_size, void* d_ws, size_t ws_size,
                              hipStream_t stream)
{
    const float* pred = (const float*)d_in[0];
    const float* targ = (const float*)d_in[1];
    float* out = (float*)d_out;

    _Float16* S5 = (_Float16*)d_ws;                       // 4*VOL4*2B = 67.1 MB
    float* l1p   = (float*)((char*)d_ws + (size_t)4 * VOL4 * 2);
    float* ssimp = l1p + K1_BLOCKS;

    k_wh<<<K1_BLOCKS, 256, 0, stream>>>(pred, targ, S5, l1p);
    k_d_ssim<<<K2_BLOCKS, 256, 0, stream>>>(S5, ssimp);
    k_final<<<1, 256, 0, stream>>>(l1p, ssimp, out);
}

// Round 20
// 48.782 us; speedup vs baseline: 2.1219x; 1.1630x over previous
//
#include <hip/hip_runtime.h>
#include <hip/hip_fp16.h>

// total = l1 + 0.5*(1 - mean(ssim3d)), volumes (4,1,128,128,128) f32
// SSIM window 11, zero-padded box sums, /11^3.
//
// 4-field formulation: A=sum(p+t), D=sum(p-t), U=sum((p+t)^2), V=sum((p-t)^2).
// f16 intermediates (unbiased RNE; final scalar err ~1e-4 << 1.8e-2).
//
// R12/R19 champion + XCD-aware block swizzle (T1):
// consecutive HW blockIdx round-robin across 8 XCDs, so logically-adjacent
// blocks (which share h/d halo reads) were on different L2s. Bijective remap
// lid=(bid%8)*(nwg/8)+bid/8 gives each XCD a contiguous logical range ->
// halo re-reads become L2 hits (latency-bound kernel -> direct win).
// R6: no last-block merge. R18: (256,8) spills preload (keep (256,4)).

#define NB 4
#define ND 128
#define NH 128
#define NW 128
#define PLANE (NH * NW)            // 16384
#define VOL (ND * PLANE)           // 2,097,152
#define VOL4 (NB * VOL)            // 8,388,608
#define K1_BLOCKS (NB * ND * 8)    // 4096 (h tiled by 16); % 8 == 0
#define K2_BLOCKS 1024             // 8 d-chunks of 16 x 128 groups; % 8 == 0
#define HS_F16 142                 // f16 row stride = 71 words (odd, 7 mod 32)

typedef _Float16 half2v __attribute__((ext_vector_type(2)));
typedef float f32x2 __attribute__((ext_vector_type(2)));

// XCD swizzle: HW assigns xcd = hw_bid % 8; give each XCD a contiguous
// logical range. Bijective because nwg % 8 == 0.
__device__ __forceinline__ int xcd_swz(int hw_bid, int chunk) {
    return (hw_bid & 7) * chunk + (hw_bid >> 3);
}

// ---------------- Kernel 1: fused W+H box sums of 4 fields + L1 partials ----
__global__ __launch_bounds__(256, 4) void k_wh(const float* __restrict__ p,
                                               const float* __restrict__ t,
                                               _Float16* __restrict__ S5,
                                               float* __restrict__ l1p)
{
    __shared__ _Float16 hs[4][16][HS_F16];   // 18,176 B
    __shared__ float red4[4];

    const int bid   = xcd_swz(blockIdx.x, K1_BLOCKS / 8);
    const int htile = bid & 7;
    const int d     = (bid >> 3) & 127;
    const int b     = bid >> 10;
    const int h0    = htile * 16;
    const int tid   = threadIdx.x;

    // ---- Stage A ----
    const int wp = tid & 63;          // lane: owns w = 2*wp, 2*wp+1
    const int c  = tid >> 6;          // wave: owns output rows hbase..hbase+3
    const int hbase = h0 + c * 4;
    const int pbase = ((b * ND + d) * NH) * NW + 2 * wp;
    const int wcol  = 2 * wp + 6;

    const f32x2 z2 = {0.f, 0.f};

    // Issue ALL 28 window loads first (guards are wave-uniform).
    f32x2 P[14], T[14];
#pragma unroll
    for (int i = 0; i < 14; ++i) {
        const int h = hbase - 5 + i;
        f32x2 pv = z2, tv = z2;
        if (h >= 0 && h < NH) {
            pv = *(const f32x2*)&p[pbase + h * NW];
            tv = *(const f32x2*)&t[pbase + h * NW];
        }
        P[i] = pv; T[i] = tv;
    }
    __builtin_amdgcn_sched_barrier(0);   // loads may not sink below this

    // halo zero (DS writes execute while loads are in flight):
    // cols 0..5 (w<0) and 134..141 (w>=128)
    for (int idx = tid; idx < 4 * 16 * 14; idx += 256) {
        const int f = idx / 224;
        const int rem = idx - f * 224;
        const int r = rem / 14;
        const int c14 = rem - r * 14;
        const int col = (c14 < 6) ? c14 : (128 + c14);
        hs[f][r][col] = (_Float16)0.f;
    }
    __builtin_amdgcn_sched_barrier(0);   // compute may not hoist above

    // Transform to A/D once; P/T die here.
    f32x2 A_[14], D_[14];
#pragma unroll
    for (int i = 0; i < 14; ++i) {
        A_[i] = P[i] + T[i];
        D_[i] = P[i] - T[i];
    }

    // L1 center taps: owned rows hbase..hbase+3 = window idx 5..8
    float l1x = 0.f, l1y = 0.f;
#pragma unroll
    for (int i = 5; i <= 8; ++i) {
        l1x += fabsf(D_[i].x);
        l1y += fabsf(D_[i].y);
    }

    f32x2 sA = z2, sD = z2, sU = z2, sV = z2;
#pragma unroll
    for (int i = 0; i < 11; ++i) {
        const f32x2 a = A_[i], dd = D_[i];
        sA += a; sD += dd;
        sU += a * a; sV += dd * dd;
    }

#define STORE4(r) do {                                                        \
        half2v o_;                                                            \
        o_[0] = (_Float16)sA.x; o_[1] = (_Float16)sA.y;                       \
        *(half2v*)&hs[0][(r)][wcol] = o_;                                     \
        o_[0] = (_Float16)sD.x; o_[1] = (_Float16)sD.y;                       \
        *(half2v*)&hs[1][(r)][wcol] = o_;                                     \
        o_[0] = (_Float16)sU.x; o_[1] = (_Float16)sU.y;                       \
        *(half2v*)&hs[2][(r)][wcol] = o_;                                     \
        o_[0] = (_Float16)sV.x; o_[1] = (_Float16)sV.y;                       \
        *(half2v*)&hs[3][(r)][wcol] = o_;                                     \
    } while (0)

    STORE4(c * 4);
#pragma unroll
    for (int k = 1; k < 4; ++k) {
        const f32x2 an = A_[10 + k], dn = D_[10 + k];
        const f32x2 ao = A_[k - 1],  do_ = D_[k - 1];
        sA += an - ao;
        sD += dn - do_;
        sU += an * an - ao * ao;
        sV += dn * dn - do_ * do_;
        STORE4(c * 4 + k);
    }
#undef STORE4

    // ---- L1 reduce: in-wave shuffle, one barrier ----
    {
        float v = l1x + l1y;
#pragma unroll
        for (int off = 32; off > 0; off >>= 1) v += __shfl_down(v, off, 64);
        if ((tid & 63) == 0) red4[tid >> 6] = v;
    }
    __syncthreads();          // publishes hs (stage A + halo) and red4
    if (tid == 0) l1p[bid] = red4[0] + red4[1] + red4[2] + red4[3];

    // ---- Stage B: W-direction sliding sums from LDS pairs, f16 stores ----
    const int ho = tid >> 4;          // 0..15
    const int wc = tid & 15;          // owns w in [8*wc, 8*wc+8)
    const size_t obase = (size_t)((b * ND + d) * NH + (h0 + ho)) * NW + wc * 8;

#pragma unroll
    for (int f = 0; f < 4; ++f) {
        half2v pr[10];
#pragma unroll
        for (int m = 0; m < 10; ++m)
            pr[m] = *(const half2v*)&hs[f][ho][8 * wc + 2 * m];
        // v[k] = H-sum at w = 8*wc - 5 + k  (halo cols are pre-zeroed)
        float v[18];
#pragma unroll
        for (int k = 0; k < 18; ++k)
            v[k] = (k & 1) ? (float)pr[(k + 1) >> 1][0] : (float)pr[k >> 1][1];
        float s = 0.f;
#pragma unroll
        for (int j = 0; j < 11; ++j) s += v[j];
        union { _Float16 h8[8]; uint4 u; } o;
        o.h8[0] = (_Float16)s;
#pragma unroll
        for (int n = 1; n < 8; ++n) {
            s += v[10 + n] - v[n - 1];
            o.h8[n] = (_Float16)s;
        }
        *(uint4*)&S5[(size_t)f * VOL4 + obase] = o.u;
    }
    // no trailing barrier: stores drain at endpgm
}

// ---------------- Kernel 2: D-direction sliding window + SSIM + reduce ------
__global__ __launch_bounds__(256) void k_d_ssim(const _Float16* __restrict__ S5,
                                                float* __restrict__ ssimp)
{
    __shared__ float red4[4];
    const float INV  = 1.0f / 1331.0f;
    const float INV2 = 1.0f / 2662.0f;
    const float C1f = 1e-4f, C2f = 9e-4f;

    const int bid = xcd_swz(blockIdx.x, K2_BLOCKS / 8);
    const int dc  = bid & 7;         // d chunk (16 deep)
    const int tid = threadIdx.x;
    const int idx = ((bid >> 3) << 8) + tid;   // 0..32767 -> (b,h,wpair)
    const int wp = idx & 63;
    const int h  = (idx >> 6) & 127;
    const int b  = idx >> 13;
    const int d0 = dc * 16;
    const size_t base0 = (size_t)b * VOL + h * NW + wp * 2;

    const _Float16* F0 = S5 + 0 * (size_t)VOL4 + base0;   // A
    const _Float16* F1 = S5 + 1 * (size_t)VOL4 + base0;   // D
    const _Float16* F2 = S5 + 2 * (size_t)VOL4 + base0;   // U
    const _Float16* F3 = S5 + 3 * (size_t)VOL4 + base0;   // V

#define LOADF(F, dd) (*(const half2v*)&(F)[(size_t)(dd) * PLANE])

    half2v ring[4][11];               // window planes, slot = (plane-(d0-5))%11
    float rsx[4] = {0.f, 0.f, 0.f, 0.f};
    float rsy[4] = {0.f, 0.f, 0.f, 0.f};

#pragma unroll
    for (int o = -5; o <= 5; ++o) {
        const int dd = d0 + o;
        half2v v0, v1, v2, v3;
        if (dd >= 0 && dd < ND) {
            v0 = LOADF(F0, dd); v1 = LOADF(F1, dd);
            v2 = LOADF(F2, dd); v3 = LOADF(F3, dd);
        } else {
            v0 = v1 = v2 = v3 = (half2v)(_Float16)0.f;
        }
        ring[0][o + 5] = v0; ring[1][o + 5] = v1;
        ring[2][o + 5] = v2; ring[3][o + 5] = v3;
        rsx[0] += (float)v0[0]; rsy[0] += (float)v0[1];
        rsx[1] += (float)v1[0]; rsy[1] += (float)v1[1];
        rsx[2] += (float)v2[0]; rsy[2] += (float)v2[1];
        rsx[3] += (float)v3[0]; rsy[3] += (float)v3[1];
    }

    float acc = 0.f;
#pragma unroll
    for (int s = 0; s < 16; ++s) {
        {
            const float muA = rsx[0] * INV, muD = rsx[1] * INV;
            const float mAA = muA * muA, mDD = muD * muD;
            const float P2 = 0.5f * (mAA - mDD);     // 2 mu_p mu_t
            const float S2 = 0.5f * (mAA + mDD);     // mu_p^2 + mu_t^2
            const float num = (P2 + C1f) * fmaf(rsx[2] - rsx[3], INV2, C2f - P2);
            const float den = (S2 + C1f) * fmaf(rsx[2] + rsx[3], INV2, C2f - S2);
            acc = fmaf(num, __builtin_amdgcn_rcpf(den), acc);
        }
        {
            const float muA = rsy[0] * INV, muD = rsy[1] * INV;
            const float mAA = muA * muA, mDD = muD * muD;
            const float P2 = 0.5f * (mAA - mDD);
            const float S2 = 0.5f * (mAA + mDD);
            const float num = (P2 + C1f) * fmaf(rsy[2] - rsy[3], INV2, C2f - P2);
            const float den = (S2 + C1f) * fmaf(rsy[2] + rsy[3], INV2, C2f - S2);
            acc = fmaf(num, __builtin_amdgcn_rcpf(den), acc);
        }

        if (s < 15) {
            const int slot = s % 11;
            const int da = d0 + 6 + s;
            half2v n0, n1, n2, n3;
            if (da < ND) {
                n0 = LOADF(F0, da); n1 = LOADF(F1, da);
                n2 = LOADF(F2, da); n3 = LOADF(F3, da);
            } else {
                n0 = n1 = n2 = n3 = (half2v)(_Float16)0.f;
            }
            rsx[0] += (float)n0[0] - (float)ring[0][slot][0];
            rsy[0] += (float)n0[1] - (float)ring[0][slot][1];
            rsx[1] += (float)n1[0] - (float)ring[1][slot][0];
            rsy[1] += (float)n1[1] - (float)ring[1][slot][1];
            rsx[2] += (float)n2[0] - (float)ring[2][slot][0];
            rsy[2] += (float)n2[1] - (float)ring[2][slot][1];
            rsx[3] += (float)n3[0] - (float)ring[3][slot][0];
            rsy[3] += (float)n3[1] - (float)ring[3][slot][1];
            ring[0][slot] = n0; ring[1][slot] = n1;
            ring[2][slot] = n2; ring[3][slot] = n3;
        }
    }
#undef LOADF

    // in-wave shuffle reduce, one barrier
    float v = acc;
#pragma unroll
    for (int off = 32; off > 0; off >>= 1) v += __shfl_down(v, off, 64);
    if ((tid & 63) == 0) red4[tid >> 6] = v;
    __syncthreads();
    if (tid == 0) ssimp[bid] = red4[0] + red4[1] + red4[2] + red4[3];
}

// ---------------- Kernel 3: final deterministic reduction -------------------
__global__ __launch_bounds__(256) void k_final(const float* __restrict__ l1p,
                                               const float* __restrict__ sp,
                                               float* __restrict__ out)
{
    __shared__ double r1[256];
    __shared__ double r2[256];
    const int tid = threadIdx.x;
    double s1 = 0.0, s2 = 0.0;
    for (int i = tid; i < K1_BLOCKS; i += 256) s1 += (double)l1p[i];
    for (int i = tid; i < K2_BLOCKS; i += 256) s2 += (double)sp[i];
    r1[tid] = s1; r2[tid] = s2;
    __syncthreads();
    for (int s = 128; s > 0; s >>= 1) {
        if (tid < s) { r1[tid] += r1[tid + s]; r2[tid] += r2[tid + s]; }
        __syncthreads();
    }
    if (tid == 0) {
        const double N = (double)VOL4;
        const double l1        = r1[0] / N;
        const double ssim_mean = r2[0] / N;
        const double ssim_loss = 1.0 - ssim_mean;
        out[0] = (float)(l1 + 0.5 * ssim_loss);  // total
        out[1] = (float)l1;                      // l1_loss
        out[2] = (float)ssim_loss;               // ssim_loss
        out[3] = 0.f;                            // reg_loss
    }
}

extern "C" void kernel_launch(void* const* d_in, const int* in_sizes, int n_in,
                              void* d_out, int out_size, void* d_ws, size_t ws_size,
                              hipStream_t stream)
{
    const float* pred = (const float*)d_in[0];
    const float* targ = (const float*)d_in[1];
    float* out = (float*)d_out;

    _Float16* S5 = (_Float16*)d_ws;                       // 4*VOL4*2B = 67.1 MB
    float* l1p   = (float*)((char*)d_ws + (size_t)4 * VOL4 * 2);
    float* ssimp = l1p + K1_BLOCKS;

    k_wh<<<K1_BLOCKS, 256, 0, stream>>>(pred, targ, S5, l1p);
    k_d_ssim<<<K2_BLOCKS, 256, 0, stream>>>(S5, ssimp);
    k_final<<<1, 256, 0, stream>>>(l1p, ssimp, out);
}